// Round 2
// baseline (50730.151 us; speedup 1.0000x reference)
//
#include <hip/hip_runtime.h>
#include <cmath>

#define H 512
#define H3 1536
#define B 128
#define LC 256
#define LT 64
#define V 27
#define EPSF 1e-8f

__device__ __forceinline__ float sigf(float x){ return 1.0f/(1.0f+expf(-x)); }

__device__ __forceinline__ float wsum(float v){
#pragma unroll
  for(int o=32;o;o>>=1) v += __shfl_down(v,o,64);
  return v;
}

// ---------- fuse W_enc into enc0 Wih (rank-2 input trick) ----------
__global__ __launch_bounds__(256) void fuse_w0(
    const float* __restrict__ Wih, const float* __restrict__ W_enc,
    const float* __restrict__ b_enc, const float* __restrict__ bih,
    float* __restrict__ F, float* __restrict__ bf){
  int wid = blockIdx.x*4 + (threadIdx.x>>6);
  int lane = threadIdx.x & 63;
  if (wid >= 2*H3) return;
  const float* w = Wih + wid*H;
  float f0=0.f, f1=0.f, fb=0.f;
  for(int k=lane;k<H;k+=64){
    float wv = w[k];
    f0 += wv*W_enc[2*k]; f1 += wv*W_enc[2*k+1]; fb += wv*b_enc[k];
  }
  f0=wsum(f0); f1=wsum(f1); fb=wsum(fb);
  if(lane==0){ F[2*wid]=f0; F[2*wid+1]=f1; bf[wid]=fb+bih[wid]; }
}

// ---------- encoder layer 0 step: hidden GEMM + rank-2 input + gates ----------
__global__ __launch_bounds__(256) void enc0_step(
    int t, const float* __restrict__ x, const float* __restrict__ F,
    const float* __restrict__ bf, const float* __restrict__ Whh,
    const float* __restrict__ bhh, float* __restrict__ y0){
  const int d = blockIdx.z;
  const int cur = d==0 ? t : (LC-1-t);
  const int prev = d==0 ? cur-1 : cur+1;
  const int u0 = blockIdx.x*16;
  const int b0 = blockIdx.y*16;
  const int tid = threadIdx.x;
  const int tx = tid & 15, ty = tid >> 4;
  __shared__ float As[16][68];
  __shared__ float Ws[48][68];
  float accr=0.f, accz=0.f, accn=0.f;
  const int TS = B*2*H;
  const float* hbase = y0 + prev*TS + d*H;           // + b*1024 + k
  const float* wbase = Whh + d*H3*H;
  for(int c=0;c<8;c++){
    int k0 = c*64;
#pragma unroll
    for(int j=0;j<4;j++){
      int i = tid + 256*j; int r = i>>6, k = i&63;
      As[r][k] = (t==0) ? 0.0f : hbase[(b0+r)*(2*H) + k0 + k];
    }
#pragma unroll
    for(int j=0;j<12;j++){
      int i = tid + 256*j; int r = i>>6, k = i&63;
      int g = r>>4, u = r&15;
      Ws[r][k] = wbase[(g*H + u0 + u)*H + k0 + k];
    }
    __syncthreads();
#pragma unroll
    for(int kk=0;kk<64;kk+=4){
      float4 a4 = *(const float4*)&As[ty][kk];
      float4 wr = *(const float4*)&Ws[tx][kk];
      float4 wz = *(const float4*)&Ws[16+tx][kk];
      float4 wn = *(const float4*)&Ws[32+tx][kk];
      accr += a4.x*wr.x + a4.y*wr.y + a4.z*wr.z + a4.w*wr.w;
      accz += a4.x*wz.x + a4.y*wz.y + a4.z*wz.z + a4.w*wz.w;
      accn += a4.x*wn.x + a4.y*wn.y + a4.z*wn.z + a4.w*wn.w;
    }
    __syncthreads();
  }
  const int b = b0 + ty, u = u0 + tx;
  const float x0 = x[b*2*LC + cur];
  const float x1 = x[b*2*LC + LC + cur];
  const int jr = d*H3 + u, jz = jr + H, jn = jz + H;
  float gir = x0*F[2*jr] + x1*F[2*jr+1] + bf[jr];
  float giz = x0*F[2*jz] + x1*F[2*jz+1] + bf[jz];
  float gin = x0*F[2*jn] + x1*F[2*jn+1] + bf[jn];
  float r = sigf(gir + accr + bhh[jr]);
  float z = sigf(giz + accz + bhh[jz]);
  float n = tanhf(gin + r*(accn + bhh[jn]));
  float hp = (t==0) ? 0.0f : hbase[b*(2*H) + u];
  y0[cur*TS + b*(2*H) + d*H + u] = (1.0f-z)*n + z*hp;
}

// ---------- encoder layer 1 step: K = 1024(input from y0) + 512(hidden) ----------
__global__ __launch_bounds__(256) void enc1_step(
    int t, const float* __restrict__ y0, const float* __restrict__ Wih,
    const float* __restrict__ Whh, const float* __restrict__ bih,
    const float* __restrict__ bhh, float* __restrict__ y1){
  const int d = blockIdx.z;
  const int cur = d==0 ? t : (LC-1-t);
  const int prev = d==0 ? cur-1 : cur+1;
  const int u0 = blockIdx.x*16;
  const int b0 = blockIdx.y*16;
  const int tid = threadIdx.x;
  const int tx = tid & 15, ty = tid >> 4;
  __shared__ float As[16][68];
  __shared__ float Ws[48][68];
  float accr=0.f, accz=0.f, accni=0.f, accnh=0.f;
  const int TS = B*2*H;
  const float* xin = y0 + cur*TS;                    // + b*1024 + k
  const float* hbase = y1 + prev*TS + d*H;
  const float* wi = Wih + d*H3*(2*H);
  const float* wh = Whh + d*H3*H;
  for(int c=0;c<16;c++){
    int k0 = c*64;
#pragma unroll
    for(int j=0;j<4;j++){
      int i = tid + 256*j; int r = i>>6, k = i&63;
      As[r][k] = xin[(b0+r)*(2*H) + k0 + k];
    }
#pragma unroll
    for(int j=0;j<12;j++){
      int i = tid + 256*j; int r = i>>6, k = i&63;
      int g = r>>4, u = r&15;
      Ws[r][k] = wi[(g*H + u0 + u)*(2*H) + k0 + k];
    }
    __syncthreads();
#pragma unroll
    for(int kk=0;kk<64;kk+=4){
      float4 a4 = *(const float4*)&As[ty][kk];
      float4 wr = *(const float4*)&Ws[tx][kk];
      float4 wz = *(const float4*)&Ws[16+tx][kk];
      float4 wn = *(const float4*)&Ws[32+tx][kk];
      accr += a4.x*wr.x + a4.y*wr.y + a4.z*wr.z + a4.w*wr.w;
      accz += a4.x*wz.x + a4.y*wz.y + a4.z*wz.z + a4.w*wz.w;
      accni += a4.x*wn.x + a4.y*wn.y + a4.z*wn.z + a4.w*wn.w;
    }
    __syncthreads();
  }
  for(int c=0;c<8;c++){
    int k0 = c*64;
#pragma unroll
    for(int j=0;j<4;j++){
      int i = tid + 256*j; int r = i>>6, k = i&63;
      As[r][k] = (t==0) ? 0.0f : hbase[(b0+r)*(2*H) + k0 + k];
    }
#pragma unroll
    for(int j=0;j<12;j++){
      int i = tid + 256*j; int r = i>>6, k = i&63;
      int g = r>>4, u = r&15;
      Ws[r][k] = wh[(g*H + u0 + u)*H + k0 + k];
    }
    __syncthreads();
#pragma unroll
    for(int kk=0;kk<64;kk+=4){
      float4 a4 = *(const float4*)&As[ty][kk];
      float4 wr = *(const float4*)&Ws[tx][kk];
      float4 wz = *(const float4*)&Ws[16+tx][kk];
      float4 wn = *(const float4*)&Ws[32+tx][kk];
      accr += a4.x*wr.x + a4.y*wr.y + a4.z*wr.z + a4.w*wr.w;
      accz += a4.x*wz.x + a4.y*wz.y + a4.z*wz.z + a4.w*wz.w;
      accnh += a4.x*wn.x + a4.y*wn.y + a4.z*wn.z + a4.w*wn.w;
    }
    __syncthreads();
  }
  const int b = b0 + ty, u = u0 + tx;
  const int jr = d*H3 + u, jz = jr + H, jn = jz + H;
  float r = sigf(accr + bih[jr] + bhh[jr]);
  float z = sigf(accz + bih[jz] + bhh[jz]);
  float n = tanhf(accni + bih[jn] + r*(accnh + bhh[jn]));
  float hp = (t==0) ? 0.0f : hbase[b*(2*H) + u];
  y1[cur*TS + b*(2*H) + d*H + u] = (1.0f-z)*n + z*hp;
}

// ---------- decoder GRU cell: K = 512(input) + 512(hidden) ----------
__global__ __launch_bounds__(256) void dec_gru(
    const float* __restrict__ xsrc, const int* __restrict__ idx,
    const float* __restrict__ hprev, float* __restrict__ hout,
    const float* __restrict__ Wih, const float* __restrict__ Whh,
    const float* __restrict__ bih, const float* __restrict__ bhh){
  const int u0 = blockIdx.x*16;
  const int b0 = blockIdx.y*16;
  const int tid = threadIdx.x;
  const int tx = tid & 15, ty = tid >> 4;
  __shared__ float As[16][68];
  __shared__ float Ws[48][68];
  float accr=0.f, accz=0.f, accni=0.f, accnh=0.f;
  for(int c=0;c<8;c++){
    int k0 = c*64;
#pragma unroll
    for(int j=0;j<4;j++){
      int i = tid + 256*j; int r = i>>6, k = i&63;
      int b = b0 + r;
      const float* base = idx ? (xsrc + idx[b]*H) : (xsrc + b*H);
      As[r][k] = base[k0 + k];
    }
#pragma unroll
    for(int j=0;j<12;j++){
      int i = tid + 256*j; int r = i>>6, k = i&63;
      int g = r>>4, u = r&15;
      Ws[r][k] = Wih[(g*H + u0 + u)*H + k0 + k];
    }
    __syncthreads();
#pragma unroll
    for(int kk=0;kk<64;kk+=4){
      float4 a4 = *(const float4*)&As[ty][kk];
      float4 wr = *(const float4*)&Ws[tx][kk];
      float4 wz = *(const float4*)&Ws[16+tx][kk];
      float4 wn = *(const float4*)&Ws[32+tx][kk];
      accr += a4.x*wr.x + a4.y*wr.y + a4.z*wr.z + a4.w*wr.w;
      accz += a4.x*wz.x + a4.y*wz.y + a4.z*wz.z + a4.w*wz.w;
      accni += a4.x*wn.x + a4.y*wn.y + a4.z*wn.z + a4.w*wn.w;
    }
    __syncthreads();
  }
  for(int c=0;c<8;c++){
    int k0 = c*64;
#pragma unroll
    for(int j=0;j<4;j++){
      int i = tid + 256*j; int r = i>>6, k = i&63;
      As[r][k] = hprev[(b0+r)*H + k0 + k];
    }
#pragma unroll
    for(int j=0;j<12;j++){
      int i = tid + 256*j; int r = i>>6, k = i&63;
      int g = r>>4, u = r&15;
      Ws[r][k] = Whh[(g*H + u0 + u)*H + k0 + k];
    }
    __syncthreads();
#pragma unroll
    for(int kk=0;kk<64;kk+=4){
      float4 a4 = *(const float4*)&As[ty][kk];
      float4 wr = *(const float4*)&Ws[tx][kk];
      float4 wz = *(const float4*)&Ws[16+tx][kk];
      float4 wn = *(const float4*)&Ws[32+tx][kk];
      accr += a4.x*wr.x + a4.y*wr.y + a4.z*wr.z + a4.w*wr.w;
      accz += a4.x*wz.x + a4.y*wz.y + a4.z*wz.z + a4.w*wz.w;
      accnh += a4.x*wn.x + a4.y*wn.y + a4.z*wn.z + a4.w*wn.w;
    }
    __syncthreads();
  }
  const int b = b0 + ty, u = u0 + tx;
  float r = sigf(accr + bih[u] + bhh[u]);
  float z = sigf(accz + bih[H+u] + bhh[H+u]);
  float n = tanhf(accni + bih[2*H+u] + r*(accnh + bhh[2*H+u]));
  float hp = hprev[b*H + u];
  hout[b*H + u] = (1.0f-z)*n + z*hp;
}

// ---------- bi_fc: v[b,l,h] = y1[l,b,:] @ W_bi[h,:] + b_bi ----------
__global__ __launch_bounds__(256) void bi_fc(
    const float* __restrict__ y1, const float* __restrict__ Wb,
    const float* __restrict__ bb, float* __restrict__ v){
  const int m0 = blockIdx.x*64;
  const int c0 = blockIdx.y*64;
  const int tid = threadIdx.x;
  const int tx = tid & 15, ty = tid >> 4;
  __shared__ float As[64][37];
  __shared__ float Bs[64][37];
  float acc[4][4] = {};
  for(int c=0;c<32;c++){
    int k0 = c*32;
#pragma unroll
    for(int j=0;j<8;j++){
      int i = tid + 256*j; int r = i>>5, k = i&31;
      As[r][k] = y1[(m0+r)*1024 + k0 + k];
    }
#pragma unroll
    for(int j=0;j<8;j++){
      int i = tid + 256*j; int r = i>>5, k = i&31;
      Bs[r][k] = Wb[(c0+r)*1024 + k0 + k];
    }
    __syncthreads();
#pragma unroll
    for(int kk=0;kk<32;kk++){
      float a0=As[ty*4+0][kk], a1=As[ty*4+1][kk], a2=As[ty*4+2][kk], a3=As[ty*4+3][kk];
      float w0=Bs[tx*4+0][kk], w1=Bs[tx*4+1][kk], w2=Bs[tx*4+2][kk], w3=Bs[tx*4+3][kk];
      acc[0][0]+=a0*w0; acc[0][1]+=a0*w1; acc[0][2]+=a0*w2; acc[0][3]+=a0*w3;
      acc[1][0]+=a1*w0; acc[1][1]+=a1*w1; acc[1][2]+=a1*w2; acc[1][3]+=a1*w3;
      acc[2][0]+=a2*w0; acc[2][1]+=a2*w1; acc[2][2]+=a2*w2; acc[2][3]+=a2*w3;
      acc[3][0]+=a3*w0; acc[3][1]+=a3*w1; acc[3][2]+=a3*w2; acc[3][3]+=a3*w3;
    }
    __syncthreads();
  }
#pragma unroll
  for(int i2=0;i2<4;i2++){
    int m = m0 + ty*4 + i2; int b = m & 127, l = m >> 7;
#pragma unroll
    for(int j2=0;j2<4;j2++){
      int cc = c0 + tx*4 + j2;
      v[(b*LC + l)*H + cc] = acc[i2][j2] + bb[cc];
    }
  }
}

__global__ __launch_bounds__(256) void vn_kernel(
    const float* __restrict__ v, float* __restrict__ vn){
  int row = blockIdx.x*4 + (threadIdx.x>>6);
  int lane = threadIdx.x & 63;
  const float* vr = v + row*H;
  float s=0.f;
#pragma unroll
  for(int j=0;j<8;j++){ float xx = vr[lane + 64*j]; s += xx*xx; }
  s = wsum(s);
  if(lane==0) vn[row] = fmaxf(sqrtf(s), EPSF);
}

__global__ __launch_bounds__(256) void init_dec(
    const float* __restrict__ y0, float* __restrict__ hA, int* __restrict__ vec_in){
  int i = blockIdx.x*256 + threadIdx.x;   // 0..131071
  int l = i / (B*H); int r = i % (B*H); int b = r / H; int u = r % H;
  hA[i] = (l==0) ? y0[(LC-1)*B*2*H + b*2*H + u]
                 : y0[b*2*H + H + u];
  if (i < B) vec_in[i] = 0;
}

// ---------- attention: cos-sim + softmax + weighted sum, one block per batch ----------
__global__ __launch_bounds__(256) void attn_step(
    const float* __restrict__ q_all, const float* __restrict__ v,
    const float* __restrict__ vn, float* __restrict__ a_out,
    float* __restrict__ attn_out, int t){
  int b = blockIdx.x; int tid = threadIdx.x;
  __shared__ float qs[512];
  __shared__ float red[256];
  __shared__ float sims[256];
  const float* q = q_all + b*H;
  float q0 = q[tid], q1 = q[tid+256];
  qs[tid]=q0; qs[tid+256]=q1;
  red[tid] = q0*q0 + q1*q1;
  __syncthreads();
  for(int s=128;s;s>>=1){ if(tid<s) red[tid]+=red[tid+s]; __syncthreads(); }
  float qn = fmaxf(sqrtf(red[0]), EPSF);
  int wave = tid>>6, lane = tid&63;
  const float* vb = v + b*LC*H;
  for(int l = wave; l < LC; l += 4){
    const float* vr = vb + l*H;
    float s=0.f;
#pragma unroll
    for(int j=0;j<8;j++) s += vr[lane+64*j]*qs[lane+64*j];
    s = wsum(s);
    if(lane==0) sims[l] = s / (vn[b*LC + l]*qn);
  }
  __syncthreads();
  red[tid] = sims[tid];
  __syncthreads();
  for(int s=128;s;s>>=1){ if(tid<s) red[tid]=fmaxf(red[tid],red[tid+s]); __syncthreads(); }
  float m = red[0];
  __syncthreads();
  float e = expf(sims[tid]-m);
  red[tid] = e;
  __syncthreads();
  for(int s=128;s;s>>=1){ if(tid<s) red[tid]+=red[tid+s]; __syncthreads(); }
  float wv = e / red[0];
  sims[tid] = wv;
  attn_out[b*LC*LT + tid*LT + t] = wv;
  __syncthreads();
  for(int h=tid; h<H; h+=256){
    float acc=0.f;
#pragma unroll 4
    for(int l=0;l<LC;l++) acc += sims[l]*vb[l*H+h];
    a_out[b*H+h]=acc;
  }
}

// ---------- attention_fc: hid = [q|a] @ W_att.T + b_att ----------
__global__ __launch_bounds__(256) void att_fc(
    const float* __restrict__ q, const float* __restrict__ a,
    const float* __restrict__ W, const float* __restrict__ bias,
    float* __restrict__ hid){
  const int m0 = blockIdx.x*32;
  const int c0 = blockIdx.y*32;
  const int tid = threadIdx.x;
  const int tx = tid & 15, ty = tid >> 4;
  __shared__ float As[32][37];
  __shared__ float Bs[32][37];
  float acc[2][2] = {};
  for(int c=0;c<32;c++){
    int k0 = c*32;
#pragma unroll
    for(int j=0;j<4;j++){
      int i = tid + 256*j; int r = i>>5, k = i&31;
      int kk2 = k0 + k;
      As[r][k] = (kk2 < 512) ? q[(m0+r)*H + kk2] : a[(m0+r)*H + kk2 - 512];
    }
#pragma unroll
    for(int j=0;j<4;j++){
      int i = tid + 256*j; int r = i>>5, k = i&31;
      Bs[r][k] = W[(c0+r)*(2*H) + k0 + k];
    }
    __syncthreads();
#pragma unroll
    for(int kk=0;kk<32;kk++){
      float a0=As[ty*2][kk], a1=As[ty*2+1][kk];
      float w0=Bs[tx*2][kk], w1=Bs[tx*2+1][kk];
      acc[0][0]+=a0*w0; acc[0][1]+=a0*w1; acc[1][0]+=a1*w0; acc[1][1]+=a1*w1;
    }
    __syncthreads();
  }
#pragma unroll
  for(int i2=0;i2<2;i2++)
#pragma unroll
    for(int j2=0;j2<2;j2++){
      int b=m0+ty*2+i2, cc=c0+tx*2+j2;
      hid[b*H+cc] = acc[i2][j2] + bias[cc];
    }
}

// ---------- decoder_fc + argmax, one block per batch ----------
__global__ __launch_bounds__(256) void logits_step(
    const float* __restrict__ hid, const float* __restrict__ W_out,
    const float* __restrict__ b_out, float* __restrict__ vec_out,
    int* __restrict__ vec_in, int t){
  int b = blockIdx.x, tid = threadIdx.x;
  __shared__ float hs[512];
  __shared__ float part[27][8];
  __shared__ float lg[27];
  hs[tid] = hid[b*H+tid]; hs[tid+256] = hid[b*H+tid+256];
  __syncthreads();
  if (tid < 216){
    int vv = tid>>3, p = tid&7;
    float s=0.f;
    const float* wr = W_out + vv*H + p*64;
    const float* hr = hs + p*64;
#pragma unroll
    for(int k=0;k<64;k++) s += hr[k]*wr[k];
    part[vv][p]=s;
  }
  __syncthreads();
  if (tid < 27){
    float s = b_out[tid];
#pragma unroll
    for(int p=0;p<8;p++) s += part[tid][p];
    lg[tid]=s;
    vec_out[b*LT*V + t*V + tid] = s;
  }
  __syncthreads();
  if (tid==0){
    float best = lg[0]; int bi=0;
    for(int v2=1;v2<V;v2++){ if(lg[v2]>best){best=lg[v2];bi=v2;} }
    vec_in[b]=bi;
  }
}

__global__ __launch_bounds__(256) void copy_hfinal(
    const float* __restrict__ hA, float* __restrict__ out){
  int i = blockIdx.x*256 + threadIdx.x;
  if (i < 2*B*H) out[i] = hA[i];
}

extern "C" void kernel_launch(void* const* d_in, const int* in_sizes, int n_in,
                              void* d_out, int out_size, void* d_ws, size_t ws_size,
                              hipStream_t stream) {
  (void)in_sizes; (void)n_in; (void)out_size;
  const float* x     = (const float*)d_in[0];
  const float* emb   = (const float*)d_in[2];
  const float* W_enc = (const float*)d_in[3];
  const float* b_enc = (const float*)d_in[4];
  const float* e0Wih = (const float*)d_in[5];
  const float* e0Whh = (const float*)d_in[6];
  const float* e0bih = (const float*)d_in[7];
  const float* e0bhh = (const float*)d_in[8];
  const float* e1Wih = (const float*)d_in[9];
  const float* e1Whh = (const float*)d_in[10];
  const float* e1bih = (const float*)d_in[11];
  const float* e1bhh = (const float*)d_in[12];
  const float* W_bi  = (const float*)d_in[13];
  const float* b_bi  = (const float*)d_in[14];
  const float* dWih  = (const float*)d_in[15];
  const float* dWhh  = (const float*)d_in[16];
  const float* dbih  = (const float*)d_in[17];
  const float* dbhh  = (const float*)d_in[18];
  const float* W_att = (const float*)d_in[19];
  const float* b_att = (const float*)d_in[20];
  const float* W_out = (const float*)d_in[21];
  const float* b_out = (const float*)d_in[22];

  // ---- workspace layout: EXACTLY 256 MiB (y0 + y1), all else aliased ----
  // y0: [LC][B][2H] fp32 (134,217,728 B)   y1: same (134,217,728 B)
  // v (67 MB)  aliases y0 slices 0..127  (y0 dead after enc1; init_dec reads
  //            slices 255 & 0 BEFORE bi_fc writes v)
  // aux (~1.7 MB) aliases y0 slices 128..131 (written only after enc1)
  // F/bf (36 KB) alias y1 start (dead before enc1 writes y1)
  const size_t need = 2ull * LC * B * 2 * H * sizeof(float);  // 268,435,456
  if (ws_size < need) return;  // graceful fail -> diagnosable absmax, no fault

  float* ws = (float*)d_ws;
  float* y0 = ws;
  float* y1 = ws + (size_t)LC*B*2*H;

  float* v  = y0;                         // 16,777,216 floats (slices 0..127)
  float* aux = y0 + (size_t)128*B*2*H;    // slices 128..131 of y0
  float* vn   = aux;                      // 32,768
  float* hA   = aux + 32768;              // 131,072
  float* hB   = hA + 2*B*H;               // 131,072
  float* abuf = hB + 2*B*H;               // 65,536
  float* hid  = abuf + B*H;               // 65,536
  int* vec_in = (int*)(hid + B*H);        // 128

  float* F  = y1;                         // 6,144
  float* bf = y1 + 2*H3*2;                // 3,072

  float* vec_out = (float*)d_out;
  float* h_final = vec_out + B*LT*V;
  float* attn    = h_final + 2*B*H;

  fuse_w0<<<768, 256, 0, stream>>>(e0Wih, W_enc, b_enc, e0bih, F, bf);

  for(int t=0;t<LC;t++)
    enc0_step<<<dim3(32,8,2), 256, 0, stream>>>(t, x, F, bf, e0Whh, e0bhh, y0);

  for(int t=0;t<LC;t++)
    enc1_step<<<dim3(32,8,2), 256, 0, stream>>>(t, y0, e1Wih, e1Whh, e1bih, e1bhh, y1);

  // order matters: init_dec reads y0[255] & y0[0]; bi_fc then overwrites
  // y0 slices 0..127 with v.
  init_dec<<<512, 256, 0, stream>>>(y0, hA, vec_in);
  bi_fc<<<dim3(512,8), 256, 0, stream>>>(y1, W_bi, b_bi, v);
  vn_kernel<<<8192, 256, 0, stream>>>(v, vn);

  for(int t=0;t<LT;t++){
    float* hin  = (t&1) ? hB : hA;
    float* hout = (t&1) ? hA : hB;
    dec_gru<<<dim3(32,8), 256, 0, stream>>>(emb, vec_in, hin, hout,
                                            dWih, dWhh, dbih, dbhh);
    dec_gru<<<dim3(32,8), 256, 0, stream>>>(hout, nullptr, hin + B*H, hout + B*H,
                                            dWih + H3*H, dWhh + H3*H, dbih + H3, dbhh + H3);
    attn_step<<<B, 256, 0, stream>>>(hout + B*H, v, vn, abuf, attn, t);
    att_fc<<<dim3(4,16), 256, 0, stream>>>(hout + B*H, abuf, W_att, b_att, hid);
    logits_step<<<B, 256, 0, stream>>>(hid, W_out, b_out, vec_out, vec_in, t);
  }
  copy_hfinal<<<512, 256, 0, stream>>>(hA, h_final);
}

// Round 3
// 24477.051 us; speedup vs baseline: 2.0726x; 2.0726x over previous
//
#include <hip/hip_runtime.h>
#include <hip/hip_bf16.h>
#include <cmath>

#define H 512
#define H3 1536
#define B 128
#define LC 256
#define LT 64
#define V 27
#define EPSF 1e-8f

typedef __attribute__((ext_vector_type(4))) float f32x4;
typedef __attribute__((ext_vector_type(8))) __bf16 bf16x8;

__device__ __forceinline__ float sigf(float x){ return 1.0f/(1.0f+expf(-x)); }

__device__ __forceinline__ float wsum(float v){
#pragma unroll
  for(int o=32;o;o>>=1) v += __shfl_down(v,o,64);
  return v;
}

// split 8 fp32 -> bf16 hi + bf16 residual lo (in-register, RNE)
__device__ __forceinline__ void split8(f32x4 a0, f32x4 a1, bf16x8& hi, bf16x8& lo){
#pragma unroll
  for(int j=0;j<4;j++){
    __hip_bfloat16 h = __float2bfloat16(a0[j]);
    hi[j] = __builtin_bit_cast(__bf16, h);
    lo[j] = __builtin_bit_cast(__bf16, __float2bfloat16(a0[j]-__bfloat162float(h)));
  }
#pragma unroll
  for(int j=0;j<4;j++){
    __hip_bfloat16 h = __float2bfloat16(a1[j]);
    hi[4+j] = __builtin_bit_cast(__bf16, h);
    lo[4+j] = __builtin_bit_cast(__bf16, __float2bfloat16(a1[j]-__bfloat162float(h)));
  }
}

__device__ __forceinline__ void loadsplit(const float* __restrict__ p, bf16x8& hi, bf16x8& lo){
  f32x4 a0 = *(const f32x4*)p;
  f32x4 a1 = *(const f32x4*)(p+4);
  split8(a0,a1,hi,lo);
}

// bf16x3: c += (ah+al)*(bh+bl), dropping al*bl  (error ~2^-16 rel)
__device__ __forceinline__ f32x4 mf3(bf16x8 ah, bf16x8 al, bf16x8 bh, bf16x8 bl, f32x4 c){
  c = __builtin_amdgcn_mfma_f32_16x16x32_bf16(ah, bh, c, 0, 0, 0);
  c = __builtin_amdgcn_mfma_f32_16x16x32_bf16(ah, bl, c, 0, 0, 0);
  c = __builtin_amdgcn_mfma_f32_16x16x32_bf16(al, bh, c, 0, 0, 0);
  return c;
}

// ---------- fuse W_enc into enc0 Wih (rank-2 input trick); F split planes ----------
__global__ __launch_bounds__(256) void fuse_w0(
    const float* __restrict__ Wih, const float* __restrict__ W_enc,
    const float* __restrict__ b_enc, const float* __restrict__ bih,
    float* __restrict__ F0, float* __restrict__ F1, float* __restrict__ bf){
  int wid = blockIdx.x*4 + (threadIdx.x>>6);
  int lane = threadIdx.x & 63;
  if (wid >= 2*H3) return;
  const float* w = Wih + (size_t)wid*H;
  float f0=0.f, f1=0.f, fb=0.f;
  for(int k=lane;k<H;k+=64){
    float wv = w[k];
    f0 += wv*W_enc[2*k]; f1 += wv*W_enc[2*k+1]; fb += wv*b_enc[k];
  }
  f0=wsum(f0); f1=wsum(f1); fb=wsum(fb);
  if(lane==0){ F0[wid]=f0; F1[wid]=f1; bf[wid]=fb+bih[wid]; }
}

// ---------- encoder layer 0 step (MFMA bf16x3, gates fused) ----------
// grid 512 = 64 m-groups (2 dir x 32 UB of 16 units) x 8 n-groups; block 64
__global__ __launch_bounds__(64) void enc0_mfma(
    int t, const float* __restrict__ x,
    const float* __restrict__ F0, const float* __restrict__ F1,
    const float* __restrict__ bf, const float* __restrict__ Whh,
    const float* __restrict__ bhh, float* __restrict__ y0){
  const int job = blockIdx.x;
  const int ng = job & 7, mg = job >> 3;
  const int d = mg >> 5, UB = mg & 31;
  const int l = threadIdx.x;
  const int lr = l & 15, lk = l >> 4;       // A/B row(col) in tile, k-quarter
  const int cur = d ? (LC-1-t) : t;
  const int prev = d ? cur+1 : cur-1;
  const int n0 = ng*16;
  const int nn = n0 + lr;
  f32x4 accR = {0.f,0.f,0.f,0.f}, accZ = accR, accN = accR;
  const float* hprev = y0 + (size_t)prev*(B*1024) + d*H;   // [n][1024] slice, +n*1024+u
  const float* wb = Whh + (size_t)d*H3*H;
  if (t > 0){
#pragma unroll 2
    for(int it=0; it<16; ++it){
      const int k0 = it*32 + lk*8;
      bf16x8 xh,xl, wh,wl;
      loadsplit(hprev + (size_t)nn*1024 + k0, xh, xl);
      loadsplit(wb + (size_t)(      UB*16 + lr)*H + k0, wh, wl); accR = mf3(wh,wl,xh,xl,accR);
      loadsplit(wb + (size_t)(H   + UB*16 + lr)*H + k0, wh, wl); accZ = mf3(wh,wl,xh,xl,accZ);
      loadsplit(wb + (size_t)(2*H + UB*16 + lr)*H + k0, wh, wl); accN = mf3(wh,wl,xh,xl,accN);
    }
  }
  // epilogue: gates.  D row = lk*4+reg, col = lr.
  const int ub = UB*16 + lk*4;
  const int j0 = d*H3 + ub;
  const float x0v = x[(size_t)nn*(2*LC) + cur];
  const float x1v = x[(size_t)nn*(2*LC) + LC + cur];
  f32x4 bhr = *(const f32x4*)(bhh + j0);
  f32x4 bhz = *(const f32x4*)(bhh + j0 + H);
  f32x4 bhn = *(const f32x4*)(bhh + j0 + 2*H);
  f32x4 bfr = *(const f32x4*)(bf + j0);
  f32x4 bfz = *(const f32x4*)(bf + j0 + H);
  f32x4 bfn = *(const f32x4*)(bf + j0 + 2*H);
  f32x4 F0r = *(const f32x4*)(F0 + j0), F1r = *(const f32x4*)(F1 + j0);
  f32x4 F0z = *(const f32x4*)(F0 + j0 + H), F1z = *(const f32x4*)(F1 + j0 + H);
  f32x4 F0n = *(const f32x4*)(F0 + j0 + 2*H), F1n = *(const f32x4*)(F1 + j0 + 2*H);
  f32x4 hp4 = {0.f,0.f,0.f,0.f};
  if (t > 0) hp4 = *(const f32x4*)(hprev + (size_t)nn*1024 + ub);
  __shared__ float st[16][17];
#pragma unroll
  for(int r=0;r<4;r++){
    float gir = x0v*F0r[r] + x1v*F1r[r] + bfr[r];
    float giz = x0v*F0z[r] + x1v*F1z[r] + bfz[r];
    float gin = x0v*F0n[r] + x1v*F1n[r] + bfn[r];
    float rr = sigf(gir + accR[r] + bhr[r]);
    float zz = sigf(giz + accZ[r] + bhz[r]);
    float nv = tanhf(gin + rr*(accN[r] + bhn[r]));
    st[lr][lk*4+r] = (1.0f-zz)*nv + zz*hp4[r];
  }
  __syncthreads();
  const int rr2 = l>>2, seg = l&3;
  f32x4 val = *(const f32x4*)&st[rr2][seg*4];
  *(f32x4*)(y0 + (size_t)cur*(B*1024) + (size_t)(n0+rr2)*1024 + d*H + UB*16 + seg*4) = val;
}

// ---------- encoder layer 1 step (K = 1024 input + 512 hidden) ----------
__global__ __launch_bounds__(64) void enc1_mfma(
    int t, const float* __restrict__ y0, float* __restrict__ y1,
    const float* __restrict__ Wih, const float* __restrict__ Whh,
    const float* __restrict__ bih, const float* __restrict__ bhh){
  const int job = blockIdx.x;
  const int ng = job & 7, mg = job >> 3;
  const int d = mg >> 5, UB = mg & 31;
  const int l = threadIdx.x;
  const int lr = l & 15, lk = l >> 4;
  const int cur = d ? (LC-1-t) : t;
  const int prev = d ? cur+1 : cur-1;
  const int n0 = ng*16;
  const int nn = n0 + lr;
  f32x4 accR = {0.f,0.f,0.f,0.f}, accZ = accR, accNI = accR, accNH = accR;
  // phase A: input from y0[cur], K=1024
  const float* xin = y0 + (size_t)cur*(B*1024);
  const float* wi = Wih + (size_t)d*H3*1024;
#pragma unroll 2
  for(int it=0; it<32; ++it){
    const int k0 = it*32 + lk*8;
    bf16x8 xh,xl, wh,wl;
    loadsplit(xin + (size_t)nn*1024 + k0, xh, xl);
    loadsplit(wi + (size_t)(      UB*16 + lr)*1024 + k0, wh, wl); accR  = mf3(wh,wl,xh,xl,accR);
    loadsplit(wi + (size_t)(H   + UB*16 + lr)*1024 + k0, wh, wl); accZ  = mf3(wh,wl,xh,xl,accZ);
    loadsplit(wi + (size_t)(2*H + UB*16 + lr)*1024 + k0, wh, wl); accNI = mf3(wh,wl,xh,xl,accNI);
  }
  // phase B: hidden from y1[prev], K=512
  const float* hprev = y1 + (size_t)prev*(B*1024) + d*H;
  const float* wh_ = Whh + (size_t)d*H3*H;
  if (t > 0){
#pragma unroll 2
    for(int it=0; it<16; ++it){
      const int k0 = it*32 + lk*8;
      bf16x8 xh,xl, wh,wl;
      loadsplit(hprev + (size_t)nn*1024 + k0, xh, xl);
      loadsplit(wh_ + (size_t)(      UB*16 + lr)*H + k0, wh, wl); accR  = mf3(wh,wl,xh,xl,accR);
      loadsplit(wh_ + (size_t)(H   + UB*16 + lr)*H + k0, wh, wl); accZ  = mf3(wh,wl,xh,xl,accZ);
      loadsplit(wh_ + (size_t)(2*H + UB*16 + lr)*H + k0, wh, wl); accNH = mf3(wh,wl,xh,xl,accNH);
    }
  }
  const int ub = UB*16 + lk*4;
  const int j0 = d*H3 + ub;
  f32x4 bir = *(const f32x4*)(bih + j0);
  f32x4 biz = *(const f32x4*)(bih + j0 + H);
  f32x4 bin = *(const f32x4*)(bih + j0 + 2*H);
  f32x4 bhr = *(const f32x4*)(bhh + j0);
  f32x4 bhz = *(const f32x4*)(bhh + j0 + H);
  f32x4 bhn = *(const f32x4*)(bhh + j0 + 2*H);
  f32x4 hp4 = {0.f,0.f,0.f,0.f};
  if (t > 0) hp4 = *(const f32x4*)(hprev + (size_t)nn*1024 + ub);
  __shared__ float st[16][17];
#pragma unroll
  for(int r=0;r<4;r++){
    float rr = sigf(accR[r] + bir[r] + bhr[r]);
    float zz = sigf(accZ[r] + biz[r] + bhz[r]);
    float nv = tanhf(accNI[r] + bin[r] + rr*(accNH[r] + bhn[r]));
    st[lr][lk*4+r] = (1.0f-zz)*nv + zz*hp4[r];
  }
  __syncthreads();
  const int rr2 = l>>2, seg = l&3;
  f32x4 val = *(const f32x4*)&st[rr2][seg*4];
  *(f32x4*)(y1 + (size_t)cur*(B*1024) + (size_t)(n0+rr2)*1024 + d*H + UB*16 + seg*4) = val;
}

// ---------- decoder GRU layer (K = 512 input + 512 hidden), grid 256 ----------
__global__ __launch_bounds__(64) void dec_gru_mfma(
    const float* __restrict__ xsrc, int xstride, const int* __restrict__ idx,
    const float* __restrict__ hprev, int hstride,
    float* __restrict__ hout, int ostride,
    const float* __restrict__ Wih, const float* __restrict__ Whh,
    const float* __restrict__ bih, const float* __restrict__ bhh){
  const int job = blockIdx.x;
  const int ng = job & 7, UB = job >> 3;     // 32 UBs
  const int l = threadIdx.x;
  const int lr = l & 15, lk = l >> 4;
  const int n0 = ng*16;
  const int nn = n0 + lr;
  f32x4 accR = {0.f,0.f,0.f,0.f}, accZ = accR, accNI = accR, accNH = accR;
  const float* xrow = idx ? (xsrc + (size_t)idx[nn]*xstride) : (xsrc + (size_t)nn*xstride);
#pragma unroll 2
  for(int it=0; it<16; ++it){
    const int k0 = it*32 + lk*8;
    bf16x8 xh,xl, wh,wl;
    loadsplit(xrow + k0, xh, xl);
    loadsplit(Wih + (size_t)(      UB*16 + lr)*H + k0, wh, wl); accR  = mf3(wh,wl,xh,xl,accR);
    loadsplit(Wih + (size_t)(H   + UB*16 + lr)*H + k0, wh, wl); accZ  = mf3(wh,wl,xh,xl,accZ);
    loadsplit(Wih + (size_t)(2*H + UB*16 + lr)*H + k0, wh, wl); accNI = mf3(wh,wl,xh,xl,accNI);
  }
#pragma unroll 2
  for(int it=0; it<16; ++it){
    const int k0 = it*32 + lk*8;
    bf16x8 xh,xl, wh,wl;
    loadsplit(hprev + (size_t)nn*hstride + k0, xh, xl);
    loadsplit(Whh + (size_t)(      UB*16 + lr)*H + k0, wh, wl); accR  = mf3(wh,wl,xh,xl,accR);
    loadsplit(Whh + (size_t)(H   + UB*16 + lr)*H + k0, wh, wl); accZ  = mf3(wh,wl,xh,xl,accZ);
    loadsplit(Whh + (size_t)(2*H + UB*16 + lr)*H + k0, wh, wl); accNH = mf3(wh,wl,xh,xl,accNH);
  }
  const int ub = UB*16 + lk*4;
  f32x4 bir = *(const f32x4*)(bih + ub);
  f32x4 biz = *(const f32x4*)(bih + ub + H);
  f32x4 bin = *(const f32x4*)(bih + ub + 2*H);
  f32x4 bhr = *(const f32x4*)(bhh + ub);
  f32x4 bhz = *(const f32x4*)(bhh + ub + H);
  f32x4 bhn = *(const f32x4*)(bhh + ub + 2*H);
  f32x4 hp4 = *(const f32x4*)(hprev + (size_t)nn*hstride + ub);
  __shared__ float st[16][17];
#pragma unroll
  for(int r=0;r<4;r++){
    float rr = sigf(accR[r] + bir[r] + bhr[r]);
    float zz = sigf(accZ[r] + biz[r] + bhz[r]);
    float nv = tanhf(accNI[r] + bin[r] + rr*(accNH[r] + bhn[r]));
    st[lr][lk*4+r] = (1.0f-zz)*nv + zz*hp4[r];
  }
  __syncthreads();
  const int rr2 = l>>2, seg = l&3;
  f32x4 val = *(const f32x4*)&st[rr2][seg*4];
  *(f32x4*)(hout + (size_t)(n0+rr2)*ostride + UB*16 + seg*4) = val;
}

// ---------- attention_fc: hid = [q|a] @ W_att.T + b_att (MFMA), grid 256 ----------
__global__ __launch_bounds__(64) void att_fc_mfma(
    const float* __restrict__ qa, const float* __restrict__ W,
    const float* __restrict__ bias, float* __restrict__ hid){
  const int job = blockIdx.x;
  const int ng = job & 7, mt = job >> 3;     // 32 row-tiles
  const int l = threadIdx.x;
  const int lr = l & 15, lk = l >> 4;
  const int n0 = ng*16;
  const int nn = n0 + lr;
  f32x4 acc = {0.f,0.f,0.f,0.f};
#pragma unroll 2
  for(int it=0; it<32; ++it){
    const int k0 = it*32 + lk*8;
    bf16x8 xh,xl, wh,wl;
    loadsplit(qa + (size_t)nn*1024 + k0, xh, xl);
    loadsplit(W + (size_t)(mt*16 + lr)*1024 + k0, wh, wl);
    acc = mf3(wh,wl,xh,xl,acc);
  }
  const int ub = mt*16 + lk*4;
  f32x4 b4 = *(const f32x4*)(bias + ub);
  __shared__ float st[16][17];
#pragma unroll
  for(int r=0;r<4;r++) st[lr][lk*4+r] = acc[r] + b4[r];
  __syncthreads();
  const int rr2 = l>>2, seg = l&3;
  f32x4 val = *(const f32x4*)&st[rr2][seg*4];
  *(f32x4*)(hid + (size_t)(n0+rr2)*H + mt*16 + seg*4) = val;
}

// ---------- bi_fc: v[b,l,h] = y1[l,b,:] @ W_bi[h,:] + b_bi (fp32 VALU) ----------
__global__ __launch_bounds__(256) void bi_fc(
    const float* __restrict__ y1, const float* __restrict__ Wb,
    const float* __restrict__ bb, float* __restrict__ v){
  const int m0 = blockIdx.x*64;
  const int c0 = blockIdx.y*64;
  const int tid = threadIdx.x;
  const int tx = tid & 15, ty = tid >> 4;
  __shared__ float As[64][37];
  __shared__ float Bs[64][37];
  float acc[4][4] = {};
  for(int c=0;c<32;c++){
    int k0 = c*32;
#pragma unroll
    for(int j=0;j<8;j++){
      int i = tid + 256*j; int r = i>>5, k = i&31;
      As[r][k] = y1[(size_t)(m0+r)*1024 + k0 + k];
    }
#pragma unroll
    for(int j=0;j<8;j++){
      int i = tid + 256*j; int r = i>>5, k = i&31;
      Bs[r][k] = Wb[(size_t)(c0+r)*1024 + k0 + k];
    }
    __syncthreads();
#pragma unroll
    for(int kk=0;kk<32;kk++){
      float a0=As[ty*4+0][kk], a1=As[ty*4+1][kk], a2=As[ty*4+2][kk], a3=As[ty*4+3][kk];
      float w0=Bs[tx*4+0][kk], w1=Bs[tx*4+1][kk], w2=Bs[tx*4+2][kk], w3=Bs[tx*4+3][kk];
      acc[0][0]+=a0*w0; acc[0][1]+=a0*w1; acc[0][2]+=a0*w2; acc[0][3]+=a0*w3;
      acc[1][0]+=a1*w0; acc[1][1]+=a1*w1; acc[1][2]+=a1*w2; acc[1][3]+=a1*w3;
      acc[2][0]+=a2*w0; acc[2][1]+=a2*w1; acc[2][2]+=a2*w2; acc[2][3]+=a2*w3;
      acc[3][0]+=a3*w0; acc[3][1]+=a3*w1; acc[3][2]+=a3*w2; acc[3][3]+=a3*w3;
    }
    __syncthreads();
  }
#pragma unroll
  for(int i2=0;i2<4;i2++){
    int m = m0 + ty*4 + i2; int b = m & 127, ll = m >> 7;
#pragma unroll
    for(int j2=0;j2<4;j2++){
      int cc = c0 + tx*4 + j2;
      v[((size_t)b*LC + ll)*H + cc] = acc[i2][j2] + bb[cc];
    }
  }
}

__global__ __launch_bounds__(256) void vn_kernel(
    const float* __restrict__ v, float* __restrict__ vn){
  int row = blockIdx.x*4 + (threadIdx.x>>6);
  int lane = threadIdx.x & 63;
  const float* vr = v + (size_t)row*H;
  float s=0.f;
#pragma unroll
  for(int j=0;j<8;j++){ float xx = vr[lane + 64*j]; s += xx*xx; }
  s = wsum(s);
  if(lane==0) vn[row] = fmaxf(sqrtf(s), EPSF);
}

__global__ __launch_bounds__(256) void init_dec2(
    const float* __restrict__ y0, float* __restrict__ h0,
    float* __restrict__ qa0, int* __restrict__ vec_in){
  int i = blockIdx.x*256 + threadIdx.x;   // 65536
  int n = i >> 9, u = i & 511;
  h0[i] = y0[(size_t)255*B*1024 + (size_t)n*1024 + u];          // hf0
  qa0[(size_t)n*1024 + u] = y0[(size_t)n*1024 + H + u];         // hb0
  if (i < B) vec_in[i] = 0;
}

// ---------- attention: cos-sim + softmax + weighted sum; q/a live in qa ----------
__global__ __launch_bounds__(256) void attn_step(
    float* __restrict__ qa_p, const float* __restrict__ v,
    const float* __restrict__ vn, float* __restrict__ attn_out, int t){
  int b = blockIdx.x; int tid = threadIdx.x;
  __shared__ float qs[512];
  __shared__ float red[256];
  __shared__ float sims[256];
  const float* q = qa_p + (size_t)b*1024;
  float q0 = q[tid], q1 = q[tid+256];
  qs[tid]=q0; qs[tid+256]=q1;
  red[tid] = q0*q0 + q1*q1;
  __syncthreads();
  for(int s=128;s;s>>=1){ if(tid<s) red[tid]+=red[tid+s]; __syncthreads(); }
  float qn = fmaxf(sqrtf(red[0]), EPSF);
  int wave = tid>>6, lane = tid&63;
  const float* vb = v + (size_t)b*LC*H;
  for(int l = wave; l < LC; l += 4){
    const float* vr = vb + (size_t)l*H;
    float s=0.f;
#pragma unroll
    for(int j=0;j<8;j++) s += vr[lane+64*j]*qs[lane+64*j];
    s = wsum(s);
    if(lane==0) sims[l] = s / (vn[b*LC + l]*qn);
  }
  __syncthreads();
  red[tid] = sims[tid];
  __syncthreads();
  for(int s=128;s;s>>=1){ if(tid<s) red[tid]=fmaxf(red[tid],red[tid+s]); __syncthreads(); }
  float m = red[0];
  __syncthreads();
  float e = expf(sims[tid]-m);
  red[tid] = e;
  __syncthreads();
  for(int s=128;s;s>>=1){ if(tid<s) red[tid]+=red[tid+s]; __syncthreads(); }
  float wv = e / red[0];
  sims[tid] = wv;
  attn_out[(size_t)b*LC*LT + (size_t)tid*LT + t] = wv;
  __syncthreads();
  for(int h=tid; h<H; h+=256){
    float acc=0.f;
#pragma unroll 4
    for(int l=0;l<LC;l++) acc += sims[l]*vb[(size_t)l*H+h];
    qa_p[(size_t)b*1024 + 512 + h] = acc;
  }
}

// ---------- decoder_fc + argmax ----------
__global__ __launch_bounds__(256) void logits_step(
    const float* __restrict__ hid, const float* __restrict__ W_out,
    const float* __restrict__ b_out, float* __restrict__ vec_out,
    int* __restrict__ vec_in, int t){
  int b = blockIdx.x, tid = threadIdx.x;
  __shared__ float hs[512];
  __shared__ float part[27][8];
  __shared__ float lg[27];
  hs[tid] = hid[(size_t)b*H+tid]; hs[tid+256] = hid[(size_t)b*H+tid+256];
  __syncthreads();
  if (tid < 216){
    int vv = tid>>3, p = tid&7;
    float s=0.f;
    const float* wr = W_out + (size_t)vv*H + p*64;
    const float* hr = hs + p*64;
#pragma unroll
    for(int k=0;k<64;k++) s += hr[k]*wr[k];
    part[vv][p]=s;
  }
  __syncthreads();
  if (tid < 27){
    float s = b_out[tid];
#pragma unroll
    for(int p=0;p<8;p++) s += part[tid][p];
    lg[tid]=s;
    vec_out[(size_t)b*LT*V + (size_t)t*V + tid] = s;
  }
  __syncthreads();
  if (tid==0){
    float best = lg[0]; int bi=0;
    for(int v2=1;v2<V;v2++){ if(lg[v2]>best){best=lg[v2];bi=v2;} }
    vec_in[b]=bi;
  }
}

__global__ __launch_bounds__(256) void copy_hfinal2(
    const float* __restrict__ h0, const float* __restrict__ qa0,
    float* __restrict__ out){
  int i = blockIdx.x*256 + threadIdx.x;  // 131072
  if (i < 65536) out[i] = h0[i];
  else {
    int k = i - 65536; int n = k>>9, u = k&511;
    out[i] = qa0[(size_t)n*1024 + u];
  }
}

extern "C" void kernel_launch(void* const* d_in, const int* in_sizes, int n_in,
                              void* d_out, int out_size, void* d_ws, size_t ws_size,
                              hipStream_t stream) {
  (void)in_sizes; (void)n_in; (void)out_size;
  const float* x     = (const float*)d_in[0];
  const float* emb   = (const float*)d_in[2];
  const float* W_enc = (const float*)d_in[3];
  const float* b_enc = (const float*)d_in[4];
  const float* e0Wih = (const float*)d_in[5];
  const float* e0Whh = (const float*)d_in[6];
  const float* e0bih = (const float*)d_in[7];
  const float* e0bhh = (const float*)d_in[8];
  const float* e1Wih = (const float*)d_in[9];
  const float* e1Whh = (const float*)d_in[10];
  const float* e1bih = (const float*)d_in[11];
  const float* e1bhh = (const float*)d_in[12];
  const float* W_bi  = (const float*)d_in[13];
  const float* b_bi  = (const float*)d_in[14];
  const float* dWih  = (const float*)d_in[15];
  const float* dWhh  = (const float*)d_in[16];
  const float* dbih  = (const float*)d_in[17];
  const float* dbhh  = (const float*)d_in[18];
  const float* W_att = (const float*)d_in[19];
  const float* b_att = (const float*)d_in[20];
  const float* W_out = (const float*)d_in[21];
  const float* b_out = (const float*)d_in[22];

  // ---- workspace: 256 MiB total (same proven map as R2) ----
  const size_t need = 2ull * LC * B * 1024 * sizeof(float);  // 268,435,456
  if (ws_size < need) return;

  float* ws = (float*)d_ws;
  float* y0 = ws;                               // [256][128][1024] fp32
  float* y1 = ws + (size_t)LC*B*1024;           // [256][128][1024] fp32

  // post-encoder aliases into y0 region:
  float* v    = y0;                             // [128][256][512] fp32 (16.8M floats)
  float* aux  = y0 + (size_t)16777216;
  float* vn   = aux;                            // 32768
  float* h0b  = vn + 32768;                     // 2 x [128][512]
  float* qa   = h0b + 2*B*H;                    // 2 x [128][1024]  (q | a)
  float* hid  = qa + 2*B*1024;                  // [128][512]
  int* vec_in = (int*)(hid + B*H);              // 128

  // F planes + fused bias live in y1 head (y1 untouched until enc1)
  float* F0 = y1;                               // 3072
  float* F1 = y1 + 2*H3;                        // 3072
  float* bf = y1 + 4*H3;                        // 3072

  float* vec_out = (float*)d_out;
  float* h_final = vec_out + (size_t)B*LT*V;
  float* attn    = h_final + 2*B*H;

  fuse_w0<<<768, 256, 0, stream>>>(e0Wih, W_enc, b_enc, e0bih, F0, F1, bf);

  for(int t=0;t<LC;t++)
    enc0_mfma<<<512, 64, 0, stream>>>(t, x, F0, F1, bf, e0Whh, e0bhh, y0);

  for(int t=0;t<LC;t++)
    enc1_mfma<<<512, 64, 0, stream>>>(t, y0, y1, e1Wih, e1Whh, e1bih, e1bhh);

  // init_dec reads y0[255] & y0[0] BEFORE bi_fc overwrites y0 with v
  init_dec2<<<256, 256, 0, stream>>>(y0, h0b, qa, vec_in);
  bi_fc<<<dim3(512,8), 256, 0, stream>>>(y1, W_bi, b_bi, v);
  vn_kernel<<<8192, 256, 0, stream>>>(v, vn);

  for(int t=0;t<LT;t++){
    const int pin = t & 1, pout = 1 - pin;
    float* h0in  = h0b + (size_t)pin*B*H;
    float* h0out = h0b + (size_t)pout*B*H;
    float* qain  = qa + (size_t)pin*B*1024;
    float* qaout = qa + (size_t)pout*B*1024;
    dec_gru_mfma<<<256, 64, 0, stream>>>(emb, H, vec_in, h0in, H, h0out, H,
                                         dWih, dWhh, dbih, dbhh);
    dec_gru_mfma<<<256, 64, 0, stream>>>(h0out, H, nullptr, qain, 1024, qaout, 1024,
                                         dWih + (size_t)H3*H, dWhh + (size_t)H3*H,
                                         dbih + H3, dbhh + H3);
    attn_step<<<B, 256, 0, stream>>>(qaout, v, vn, attn, t);
    att_fc_mfma<<<256, 64, 0, stream>>>(qaout, W_att, b_att, hid);
    logits_step<<<B, 256, 0, stream>>>(hid, W_out, b_out, vec_out, vec_in, t);
  }
  // after t=63 (odd): final states in slot 0
  copy_hfinal2<<<512, 256, 0, stream>>>(h0b, qa, h_final);
}

// Round 4
// 18896.284 us; speedup vs baseline: 2.6847x; 1.2953x over previous
//
#include <hip/hip_runtime.h>
#include <hip/hip_bf16.h>
#include <cmath>

#define H 512
#define H3 1536
#define B 128
#define LC 256
#define LT 64
#define V 27
#define EPSF 1e-8f

typedef __attribute__((ext_vector_type(4))) float f32x4;
typedef __attribute__((ext_vector_type(8))) __bf16 bf16x8;
typedef __attribute__((ext_vector_type(8))) unsigned short u16x8;
typedef unsigned short ushort_t;

__device__ __forceinline__ float sigf(float x){ return 1.0f/(1.0f+expf(-x)); }

__device__ __forceinline__ float wsum(float v){
#pragma unroll
  for(int o=32;o;o>>=1) v += __shfl_down(v,o,64);
  return v;
}

__device__ __forceinline__ ushort_t f2bu(float f){
  __hip_bfloat16 h = __float2bfloat16(f);
  return __builtin_bit_cast(ushort_t, h);
}
__device__ __forceinline__ float bu2f(ushort_t u){
  return __bfloat162float(__builtin_bit_cast(__hip_bfloat16, u));
}
__device__ __forceinline__ bf16x8 ldg8(const ushort_t* p){
  return __builtin_bit_cast(bf16x8, *(const u16x8*)p);
}

// fragment index inside a packed plane: tile (m or n), kiter, lane -> elem offset
__device__ __forceinline__ size_t pidx(int tile, int KITn, int kit, int l){
  return ((((size_t)tile*KITn + kit)*64) + l)*8;
}
// element index (row r_=batch-or-row, col k) in packed plane
__device__ __forceinline__ size_t eidx(int r_, int k, int KITn){
  int mt=r_>>4, lr=r_&15, kit=k>>5, lk=(k>>3)&3, e=k&7;
  return (((size_t)(mt*KITn+kit)*64)+lk*16+lr)*8+e;
}

// bf16x3: c += (ah+al)*(bh+bl) dropping al*bl
__device__ __forceinline__ f32x4 mf3(bf16x8 ah, bf16x8 al, bf16x8 bh, bf16x8 bl, f32x4 c){
  c = __builtin_amdgcn_mfma_f32_16x16x32_bf16(ah, bh, c, 0, 0, 0);
  c = __builtin_amdgcn_mfma_f32_16x16x32_bf16(ah, bl, c, 0, 0, 0);
  c = __builtin_amdgcn_mfma_f32_16x16x32_bf16(al, bh, c, 0, 0, 0);
  return c;
}

// ---------------- pack fp32 [M rows, ld stride] -> bf16 hi/lo fragment planes ----------------
__global__ __launch_bounds__(256) void pack_w(
    const float* __restrict__ src, int ld, int M, int K,
    ushort_t* __restrict__ dh, ushort_t* __restrict__ dl){
  int i = blockIdx.x*256 + threadIdx.x;
  if (i >= M*K) return;
  int row = i / K, col = i - row*K;
  float w = src[(size_t)row*ld + col];
  ushort_t hi = f2bu(w);
  ushort_t lo = f2bu(w - bu2f(hi));
  size_t idx = eidx(row, col, K>>5);
  dh[idx] = hi; dl[idx] = lo;
}

// emb pack: [27][512] -> [v][kit16][lk4][8]
__global__ __launch_bounds__(256) void pack_emb(
    const float* __restrict__ src, ushort_t* __restrict__ dh, ushort_t* __restrict__ dl){
  int i = blockIdx.x*256 + threadIdx.x;
  if (i >= V*H) return;
  int vv = i >> 9, u = i & 511;
  float w = src[i];
  ushort_t hi = f2bu(w);
  ushort_t lo = f2bu(w - bu2f(hi));
  size_t idx = (((size_t)vv*16 + (u>>5))*4 + ((u>>3)&3))*8 + (u&7);
  dh[idx] = hi; dl[idx] = lo;
}

// ---------------- fuse W_enc into enc0 Wih (rank-2), fp32 outputs ----------------
__global__ __launch_bounds__(256) void fuse_w0(
    const float* __restrict__ Wih, const float* __restrict__ W_enc,
    const float* __restrict__ b_enc, const float* __restrict__ bih,
    float* __restrict__ F0, float* __restrict__ F1, float* __restrict__ bf){
  int wid = blockIdx.x*4 + (threadIdx.x>>6);
  int lane = threadIdx.x & 63;
  if (wid >= 2*H3) return;
  const float* w = Wih + (size_t)wid*H;
  float f0=0.f, f1=0.f, fb=0.f;
  for(int k=lane;k<H;k+=64){
    float wv = w[k];
    f0 += wv*W_enc[2*k]; f1 += wv*W_enc[2*k+1]; fb += wv*b_enc[k];
  }
  f0=wsum(f0); f1=wsum(f1); fb=wsum(fb);
  if(lane==0){ F0[wid]=f0; F1[wid]=f1; bf[wid]=fb+bih[wid]; }
}

// ---------------- enc0 step: grid 256 (mb 0..63 x q 0..3), 256 thr ----------------
__global__ __launch_bounds__(256) void enc0_step(
    int t, const float* __restrict__ x,
    const float* __restrict__ F0, const float* __restrict__ F1, const float* __restrict__ bfE,
    const ushort_t* __restrict__ Wh, const ushort_t* __restrict__ Wl,
    const float* __restrict__ bhh,
    ushort_t* __restrict__ Yh, ushort_t* __restrict__ Yl,
    float* __restrict__ h0f, float* __restrict__ hb0){
  const int blk = blockIdx.x;
  const int q = blk & 3, mb = blk >> 2;
  const int d = mb >> 5, ut = mb & 31;
  const int u0 = ut*16, n0 = q*32;
  const int tid = threadIdx.x, wid = tid>>6, l = tid&63, lr = l&15, lk = l>>4;
  const int cur = d ? (LC-1-t) : t;
  const int prev = d ? cur+1 : cur-1;
  __shared__ ushort_t ldsB[2][8][2][2][64][8];
  __shared__ float epi[4][16][32];
  f32x4 acc0 = {0,0,0,0}, acc1 = acc0;
  const size_t ysl = (size_t)B*1024;
  const ushort_t* Bh = Yh + (size_t)prev*ysl;
  const ushort_t* Bl = Yl + (size_t)prev*ysl;
  if (t > 0){
    const int nch = 2;                 // 16 kits / 8
    if (wid == 3){
#pragma unroll
      for (int j=0;j<32;j++){
        int kj=j>>2, ntj=(j>>1)&1, pl=j&1;
        const ushort_t* s = (pl?Bl:Bh) + pidx(q*2+ntj, 32, d*16+kj, l);
        *(u16x8*)&ldsB[0][kj][ntj][pl][l][0] = *(const u16x8*)s;
      }
    }
    __syncthreads();
    for (int c=0;c<nch;c++){
      if (wid==3){
        if (c+1<nch){
#pragma unroll
          for (int j=0;j<32;j++){
            int kj=j>>2, ntj=(j>>1)&1, pl=j&1;
            const ushort_t* s = (pl?Bl:Bh) + pidx(q*2+ntj, 32, d*16+(c+1)*8+kj, l);
            *(u16x8*)&ldsB[(c+1)&1][kj][ntj][pl][l][0] = *(const u16x8*)s;
          }
        }
      } else {
        const int g = wid;
        const int mt = d*96 + g*32 + ut;
#pragma unroll 2
        for (int kj=0;kj<8;kj++){
          int kk = c*8+kj;
          bf16x8 ah = ldg8(Wh + pidx(mt,16,kk,l));
          bf16x8 al = ldg8(Wl + pidx(mt,16,kk,l));
          bf16x8 b0h = __builtin_bit_cast(bf16x8, *(const u16x8*)&ldsB[c&1][kj][0][0][l][0]);
          bf16x8 b0l = __builtin_bit_cast(bf16x8, *(const u16x8*)&ldsB[c&1][kj][0][1][l][0]);
          bf16x8 b1h = __builtin_bit_cast(bf16x8, *(const u16x8*)&ldsB[c&1][kj][1][0][l][0]);
          bf16x8 b1l = __builtin_bit_cast(bf16x8, *(const u16x8*)&ldsB[c&1][kj][1][1][l][0]);
          acc0 = mf3(ah,al,b0h,b0l,acc0);
          acc1 = mf3(ah,al,b1h,b1l,acc1);
        }
      }
      __syncthreads();
    }
  }
  if (wid<3){
#pragma unroll
    for(int r2=0;r2<4;r2++){
      epi[wid][lk*4+r2][lr]    = acc0[r2];
      epi[wid][lk*4+r2][16+lr] = acc1[r2];
    }
  }
  __syncthreads();
  for (int e2=tid; e2<512; e2+=256){
    int u = e2>>5, bs = e2&31, b = n0+bs;
    int uu = u0+u;
    int j = d*H3 + uu;
    float x0v = x[(size_t)b*512 + cur];
    float x1v = x[(size_t)b*512 + 256 + cur];
    float gr = x0v*F0[j]      + x1v*F1[j]      + bfE[j];
    float gz = x0v*F0[j+512]  + x1v*F1[j+512]  + bfE[j+512];
    float gn = x0v*F0[j+1024] + x1v*F1[j+1024] + bfE[j+1024];
    float hp = 0.f;
    size_t ei = eidx(b, d*512+uu, 32);
    if (t>0) hp = bu2f(Bh[ei]) + bu2f(Bl[ei]);
    float rr = sigf(gr + epi[0][u][bs] + bhh[j]);
    float zz = sigf(gz + epi[1][u][bs] + bhh[j+512]);
    float nv = tanhf(gn + rr*(epi[2][u][bs] + bhh[j+1024]));
    float h = (1.0f-zz)*nv + zz*hp;
    size_t oi = (size_t)cur*ysl + ei;
    ushort_t hh = f2bu(h);
    Yh[oi]=hh; Yl[oi]=f2bu(h - bu2f(hh));
    if (d==0 && cur==LC-1) h0f[(size_t)b*512+uu]=h;
    if (d==1 && cur==0)    hb0[(size_t)b*512+uu]=h;
  }
}

// ---------------- enc1 step + fused bi_fc v-accumulation ----------------
// grid 320: blk<256 gate-blocks; blk>=256 v-blocks. t in [0,256].
__global__ __launch_bounds__(256) void enc1_step(
    int t,
    const ushort_t* __restrict__ Yh, const ushort_t* __restrict__ Yl,
    const ushort_t* __restrict__ Hinh, const ushort_t* __restrict__ Hinl,
    ushort_t* __restrict__ Houth, ushort_t* __restrict__ Houtl,
    const ushort_t* __restrict__ Wxh, const ushort_t* __restrict__ Wxl,
    const ushort_t* __restrict__ Whh_, const ushort_t* __restrict__ Whl,
    const float* __restrict__ bih, const float* __restrict__ bhh,
    const ushort_t* __restrict__ Bih, const ushort_t* __restrict__ Bil,
    const float* __restrict__ b_bi, float* __restrict__ v){
  const int tid = threadIdx.x, wid = tid>>6, l = tid&63, lr = l&15, lk = l>>4;
  const int blk = blockIdx.x;
  if (blk < 256){
    if (t >= LC) return;
    const int q = blk & 3, mb = blk >> 2;
    const int d = mb >> 5, ut = mb & 31;
    const int u0 = ut*16, n0 = q*32;
    const int cur = d ? (LC-1-t) : t;
    __shared__ ushort_t ldsB[2][8][2][2][64][8];
    __shared__ float epi[4][16][32];
    f32x4 aI0 = {0,0,0,0}, aI1 = aI0, aH0 = aI0, aH1 = aI0;
    const size_t ysl = (size_t)B*1024;
    const ushort_t* Xh = Yh + (size_t)cur*ysl;
    const ushort_t* Xl = Yl + (size_t)cur*ysl;
    const int nkit = (t>0) ? 48 : 32;
    const int nch = nkit >> 3;
    if (wid == 3){
#pragma unroll
      for (int j=0;j<32;j++){
        int kj=j>>2, ntj=(j>>1)&1, pl=j&1;
        const ushort_t* s = (pl?Xl:Xh) + pidx(q*2+ntj, 32, kj, l);
        *(u16x8*)&ldsB[0][kj][ntj][pl][l][0] = *(const u16x8*)s;
      }
    }
    __syncthreads();
    for (int c=0;c<nch;c++){
      if (wid==3){
        if (c+1<nch){
#pragma unroll
          for (int j=0;j<32;j++){
            int kj=j>>2, ntj=(j>>1)&1, pl=j&1;
            int kk = (c+1)*8+kj;
            const ushort_t* sh2; const ushort_t* sl2; int skit;
            if (kk < 32){ sh2=Xh; sl2=Xl; skit=kk; }
            else { sh2=Hinh; sl2=Hinl; skit=d*16+kk-32; }
            const ushort_t* s = (pl?sl2:sh2) + pidx(q*2+ntj, 32, skit, l);
            *(u16x8*)&ldsB[(c+1)&1][kj][ntj][pl][l][0] = *(const u16x8*)s;
          }
        }
      } else {
        const int g = wid;
        const int mt = d*96 + g*32 + ut;
#pragma unroll 2
        for (int kj=0;kj<8;kj++){
          int kk = c*8+kj;
          bf16x8 ah, al;
          if (kk < 32){ ah = ldg8(Wxh + pidx(mt,32,kk,l)); al = ldg8(Wxl + pidx(mt,32,kk,l)); }
          else        { ah = ldg8(Whh_ + pidx(mt,16,kk-32,l)); al = ldg8(Whl + pidx(mt,16,kk-32,l)); }
          bf16x8 b0h = __builtin_bit_cast(bf16x8, *(const u16x8*)&ldsB[c&1][kj][0][0][l][0]);
          bf16x8 b0l = __builtin_bit_cast(bf16x8, *(const u16x8*)&ldsB[c&1][kj][0][1][l][0]);
          bf16x8 b1h = __builtin_bit_cast(bf16x8, *(const u16x8*)&ldsB[c&1][kj][1][0][l][0]);
          bf16x8 b1l = __builtin_bit_cast(bf16x8, *(const u16x8*)&ldsB[c&1][kj][1][1][l][0]);
          if (g==2 && kk>=32){
            aH0 = mf3(ah,al,b0h,b0l,aH0);
            aH1 = mf3(ah,al,b1h,b1l,aH1);
          } else {
            aI0 = mf3(ah,al,b0h,b0l,aI0);
            aI1 = mf3(ah,al,b1h,b1l,aI1);
          }
        }
      }
      __syncthreads();
    }
    if (wid<3){
#pragma unroll
      for(int r2=0;r2<4;r2++){
        epi[wid][lk*4+r2][lr]    = aI0[r2];
        epi[wid][lk*4+r2][16+lr] = aI1[r2];
        if (wid==2){
          epi[3][lk*4+r2][lr]    = aH0[r2];
          epi[3][lk*4+r2][16+lr] = aH1[r2];
        }
      }
    }
    __syncthreads();
    for (int e2=tid; e2<512; e2+=256){
      int u = e2>>5, bs = e2&31, b = n0+bs;
      int uu = u0+u;
      int j = d*H3 + uu;
      float hp = 0.f;
      size_t ei = eidx(b, d*512+uu, 32);
      if (t>0) hp = bu2f(Hinh[ei]) + bu2f(Hinl[ei]);
      float rr = sigf(epi[0][u][bs] + bih[j] + bhh[j]);
      float zz = sigf(epi[1][u][bs] + bih[j+512] + bhh[j+512]);
      float nv = tanhf(epi[2][u][bs] + bih[j+1024] + rr*(epi[3][u][bs] + bhh[j+1024]));
      float h = (1.0f-zz)*nv + zz*hp;
      ushort_t hh = f2bu(h);
      Houth[ei]=hh; Houtl[ei]=f2bu(h - bu2f(hh));
    }
  } else {
    // v-block: v[:, l_, :] (+)= h_prev(dir d) @ Wbi-half + (first ? b_bi : 0)
    if (t == 0) return;
    const int vb2 = blk - 256;
    const int q = vb2 & 3, vb = vb2 >> 2;
    const int d = vb >> 3, hbase = (vb&7)*64;
    const int n0 = q*32;
    const int mt = d*32 + (vb&7)*4 + wid;
    f32x4 a0 = {0,0,0,0}, a1 = a0;
#pragma unroll 2
    for (int kit=0;kit<16;kit++){
      bf16x8 ah = ldg8(Bih + pidx(mt,16,kit,l));
      bf16x8 al = ldg8(Bil + pidx(mt,16,kit,l));
      bf16x8 b0h = ldg8(Hinh + pidx(q*2+0,32,d*16+kit,l));
      bf16x8 b0l = ldg8(Hinl + pidx(q*2+0,32,d*16+kit,l));
      bf16x8 b1h = ldg8(Hinh + pidx(q*2+1,32,d*16+kit,l));
      bf16x8 b1l = ldg8(Hinl + pidx(q*2+1,32,d*16+kit,l));
      a0 = mf3(ah,al,b0h,b0l,a0);
      a1 = mf3(ah,al,b1h,b1l,a1);
    }
    const int l_ = (d==0) ? (t-1) : (LC-t);
    const bool first = (t <= 128);
#pragma unroll
    for (int r2=0;r2<4;r2++){
      int hh = hbase + wid*16 + lk*4 + r2;
      int b0 = n0 + lr, b1 = n0 + 16 + lr;
      size_t va0 = ((size_t)b0*LC + l_)*512 + hh;
      size_t va1 = ((size_t)b1*LC + l_)*512 + hh;
      if (first){ v[va0] = a0[r2] + b_bi[hh]; v[va1] = a1[r2] + b_bi[hh]; }
      else      { v[va0] += a0[r2];           v[va1] += a1[r2]; }
    }
  }
}

// ---------------- decoder GRU layer: grid 128 (ut x q), 256 thr ----------------
// gather-mode: idxg!=null -> x from emb pack (per-lane gather); else x staged from Xh/Xl (KITx)
__global__ __launch_bounds__(256) void dec_gru(
    const int* __restrict__ idxg,
    const ushort_t* __restrict__ Exh, const ushort_t* __restrict__ Exl,
    const ushort_t* __restrict__ Xh, const ushort_t* __restrict__ Xl, int KITx,
    const ushort_t* __restrict__ Hinh, const ushort_t* __restrict__ Hinl, int KITh,
    ushort_t* __restrict__ Houth, ushort_t* __restrict__ Houtl, int KITo,
    const ushort_t* __restrict__ Axh, const ushort_t* __restrict__ Axl,
    const ushort_t* __restrict__ Ahh, const ushort_t* __restrict__ Ahl,
    const float* __restrict__ bih, const float* __restrict__ bhh){
  const int blk = blockIdx.x;
  const int q = blk & 3, ut = blk >> 2;
  const int u0 = ut*16, n0 = q*32;
  const int tid = threadIdx.x, wid = tid>>6, l = tid&63, lr = l&15, lk = l>>4;
  __shared__ ushort_t ldsB[2][8][2][2][64][8];
  __shared__ float epi[4][16][32];
  f32x4 aI0 = {0,0,0,0}, aI1 = aI0, aH0 = aI0, aH1 = aI0;
  const bool gather = (idxg != nullptr);
  const int nstage = gather ? 16 : 32;   // staged kits (h only, or x+h)
  const int nch = nstage >> 3;
  if (wid == 3){
#pragma unroll
    for (int j=0;j<32;j++){
      int kj=j>>2, ntj=(j>>1)&1, pl=j&1;
      const ushort_t* sh2; const ushort_t* sl2; int skit; int KITn;
      if (gather || 0*8+kj >= 16){ sh2=Hinh; sl2=Hinl; skit=(gather? kj : kj-16); KITn=KITh; }
      else { sh2=Xh; sl2=Xl; skit=kj; KITn=KITx; }
      if (gather){ sh2=Hinh; sl2=Hinl; skit=kj; KITn=KITh; }
      const ushort_t* s = (pl?sl2:sh2) + pidx(q*2+ntj, KITn, skit, l);
      *(u16x8*)&ldsB[0][kj][ntj][pl][l][0] = *(const u16x8*)s;
    }
  } else if (gather){
    // x-phase by compute waves: emb gather, K=512
    const int g = wid;
    const int mt = g*32 + ut;
    int ib0 = idxg[n0 + lr], ib1 = idxg[n0 + 16 + lr];
#pragma unroll 2
    for (int kit=0;kit<16;kit++){
      bf16x8 ah = ldg8(Axh + pidx(mt,16,kit,l));
      bf16x8 al = ldg8(Axl + pidx(mt,16,kit,l));
      size_t e0 = (((size_t)ib0*16 + kit)*4 + lk)*8;
      size_t e1 = (((size_t)ib1*16 + kit)*4 + lk)*8;
      bf16x8 b0h = ldg8(Exh + e0), b0l = ldg8(Exl + e0);
      bf16x8 b1h = ldg8(Exh + e1), b1l = ldg8(Exl + e1);
      aI0 = mf3(ah,al,b0h,b0l,aI0);
      aI1 = mf3(ah,al,b1h,b1l,aI1);
    }
  }
  __syncthreads();
  for (int c=0;c<nch;c++){
    if (wid==3){
      if (c+1<nch){
#pragma unroll
        for (int j=0;j<32;j++){
          int kj=j>>2, ntj=(j>>1)&1, pl=j&1;
          int kk = (c+1)*8+kj;
          const ushort_t* sh2; const ushort_t* sl2; int skit; int KITn;
          if (gather){ sh2=Hinh; sl2=Hinl; skit=kk; KITn=KITh; }
          else if (kk < 16){ sh2=Xh; sl2=Xl; skit=kk; KITn=KITx; }
          else { sh2=Hinh; sl2=Hinl; skit=kk-16; KITn=KITh; }
          const ushort_t* s = (pl?sl2:sh2) + pidx(q*2+ntj, KITn, skit, l);
          *(u16x8*)&ldsB[(c+1)&1][kj][ntj][pl][l][0] = *(const u16x8*)s;
        }
      }
    } else {
      const int g = wid;
      const int mt = g*32 + ut;
#pragma unroll 2
      for (int kj=0;kj<8;kj++){
        int kk = c*8+kj;
        bool hphase = gather ? true : (kk >= 16);
        int akit = gather ? kk : (hphase ? kk-16 : kk);
        bf16x8 ah, al;
        if (hphase){ ah = ldg8(Ahh + pidx(mt,16,akit,l)); al = ldg8(Ahl + pidx(mt,16,akit,l)); }
        else       { ah = ldg8(Axh + pidx(mt,16,akit,l)); al = ldg8(Axl + pidx(mt,16,akit,l)); }
        bf16x8 b0h = __builtin_bit_cast(bf16x8, *(const u16x8*)&ldsB[c&1][kj][0][0][l][0]);
        bf16x8 b0l = __builtin_bit_cast(bf16x8, *(const u16x8*)&ldsB[c&1][kj][0][1][l][0]);
        bf16x8 b1h = __builtin_bit_cast(bf16x8, *(const u16x8*)&ldsB[c&1][kj][1][0][l][0]);
        bf16x8 b1l = __builtin_bit_cast(bf16x8, *(const u16x8*)&ldsB[c&1][kj][1][1][l][0]);
        if (g==2 && hphase){
          aH0 = mf3(ah,al,b0h,b0l,aH0);
          aH1 = mf3(ah,al,b1h,b1l,aH1);
        } else {
          aI0 = mf3(ah,al,b0h,b0l,aI0);
          aI1 = mf3(ah,al,b1h,b1l,aI1);
        }
      }
    }
    __syncthreads();
  }
  if (wid<3){
#pragma unroll
    for(int r2=0;r2<4;r2++){
      epi[wid][lk*4+r2][lr]    = aI0[r2];
      epi[wid][lk*4+r2][16+lr] = aI1[r2];
      if (wid==2){
        epi[3][lk*4+r2][lr]    = aH0[r2];
        epi[3][lk*4+r2][16+lr] = aH1[r2];
      }
    }
  }
  __syncthreads();
  for (int e2=tid; e2<512; e2+=256){
    int u = e2>>5, bs = e2&31, b = n0+bs;
    int uu = u0+u;
    size_t ehi = eidx(b, uu, KITh);
    float hp = bu2f(Hinh[ehi]) + bu2f(Hinl[ehi]);
    float rr = sigf(epi[0][u][bs] + bih[uu] + bhh[uu]);
    float zz = sigf(epi[1][u][bs] + bih[uu+512] + bhh[uu+512]);
    float nv = tanhf(epi[2][u][bs] + bih[uu+1024] + rr*(epi[3][u][bs] + bhh[uu+1024]));
    float h = (1.0f-zz)*nv + zz*hp;
    size_t eo = eidx(b, uu, KITo);
    ushort_t hh = f2bu(h);
    Houth[eo]=hh; Houtl[eo]=f2bu(h - bu2f(hh));
  }
}

// ---------------- attention: cos-sim + softmax + wsum; q from qa-pack, a -> qa-pack ----------------
__global__ __launch_bounds__(256) void attn_step(
    const ushort_t* __restrict__ Qh, const ushort_t* __restrict__ Ql,
    ushort_t* __restrict__ QAh, ushort_t* __restrict__ QAl,
    const float* __restrict__ v, const float* __restrict__ vn,
    float* __restrict__ attn_out, int t){
  int b = blockIdx.x; int tid = threadIdx.x;
  __shared__ float qs[512];
  __shared__ float red[256];
  __shared__ float sims[256];
  int u1 = tid, u2 = tid+256;
  float q0 = bu2f(Qh[eidx(b,u1,32)]) + bu2f(Ql[eidx(b,u1,32)]);
  float q1 = bu2f(Qh[eidx(b,u2,32)]) + bu2f(Ql[eidx(b,u2,32)]);
  qs[u1]=q0; qs[u2]=q1;
  red[tid] = q0*q0 + q1*q1;
  __syncthreads();
  for(int s=128;s;s>>=1){ if(tid<s) red[tid]+=red[tid+s]; __syncthreads(); }
  float qn = fmaxf(sqrtf(red[0]), EPSF);
  int wave = tid>>6, lane = tid&63;
  const float* vb = v + (size_t)b*LC*H;
  for(int l2 = wave; l2 < LC; l2 += 4){
    const float* vr = vb + (size_t)l2*H;
    float s=0.f;
#pragma unroll
    for(int j=0;j<8;j++) s += vr[lane+64*j]*qs[lane+64*j];
    s = wsum(s);
    if(lane==0) sims[l2] = s / (vn[b*LC + l2]*qn);
  }
  __syncthreads();
  red[tid] = sims[tid];
  __syncthreads();
  for(int s=128;s;s>>=1){ if(tid<s) red[tid]=fmaxf(red[tid],red[tid+s]); __syncthreads(); }
  float m = red[0];
  __syncthreads();
  float e = expf(sims[tid]-m);
  red[tid] = e;
  __syncthreads();
  for(int s=128;s;s>>=1){ if(tid<s) red[tid]+=red[tid+s]; __syncthreads(); }
  float wv = e / red[0];
  sims[tid] = wv;
  attn_out[(size_t)b*LC*LT + (size_t)tid*LT + t] = wv;
  __syncthreads();
  for(int h=tid; h<H; h+=256){
    float acc=0.f;
#pragma unroll 4
    for(int l2=0;l2<LC;l2++) acc += sims[l2]*vb[(size_t)l2*H+h];
    size_t ea = eidx(b, 512+h, 32);
    ushort_t hh = f2bu(acc);
    QAh[ea] = hh; QAl[ea] = f2bu(acc - bu2f(hh));
  }
}

// ---------------- attention_fc: hid = qa @ W_att.T + b_att, grid 32 ----------------
__global__ __launch_bounds__(256) void att_fc(
    const ushort_t* __restrict__ QAh, const ushort_t* __restrict__ QAl,
    const ushort_t* __restrict__ Wh, const ushort_t* __restrict__ Wl,
    const float* __restrict__ bias, float* __restrict__ hid){
  const int blk = blockIdx.x;
  const int q = blk & 3, mbq = blk >> 2;
  const int tid = threadIdx.x, wid = tid>>6, l = tid&63, lr = l&15, lk = l>>4;
  const int mt = mbq*4 + wid;
  const int n0 = q*32;
  f32x4 a0 = {0,0,0,0}, a1 = a0;
#pragma unroll 2
  for (int kit=0;kit<32;kit++){
    bf16x8 ah = ldg8(Wh + pidx(mt,32,kit,l));
    bf16x8 al = ldg8(Wl + pidx(mt,32,kit,l));
    bf16x8 b0h = ldg8(QAh + pidx(q*2+0,32,kit,l));
    bf16x8 b0l = ldg8(QAl + pidx(q*2+0,32,kit,l));
    bf16x8 b1h = ldg8(QAh + pidx(q*2+1,32,kit,l));
    bf16x8 b1l = ldg8(QAl + pidx(q*2+1,32,kit,l));
    a0 = mf3(ah,al,b0h,b0l,a0);
    a1 = mf3(ah,al,b1h,b1l,a1);
  }
#pragma unroll
  for (int r2=0;r2<4;r2++){
    int hh = mt*16 + lk*4 + r2;
    hid[(size_t)(n0+lr)*H + hh]    = a0[r2] + bias[hh];
    hid[(size_t)(n0+16+lr)*H + hh] = a1[r2] + bias[hh];
  }
}

// ---------------- decoder_fc + argmax ----------------
__global__ __launch_bounds__(256) void logits_step(
    const float* __restrict__ hid, const float* __restrict__ W_out,
    const float* __restrict__ b_out, float* __restrict__ vec_out,
    int* __restrict__ vec_in, int t){
  int b = blockIdx.x, tid = threadIdx.x;
  __shared__ float hs[512];
  __shared__ float part[27][8];
  __shared__ float lg[27];
  hs[tid] = hid[(size_t)b*H+tid]; hs[tid+256] = hid[(size_t)b*H+tid+256];
  __syncthreads();
  if (tid < 216){
    int vv = tid>>3, p = tid&7;
    float s=0.f;
    const float* wr = W_out + (size_t)vv*H + p*64;
    const float* hr = hs + p*64;
#pragma unroll
    for(int k=0;k<64;k++) s += hr[k]*wr[k];
    part[vv][p]=s;
  }
  __syncthreads();
  if (tid < 27){
    float s = b_out[tid];
#pragma unroll
    for(int p=0;p<8;p++) s += part[tid][p];
    lg[tid]=s;
    vec_out[(size_t)b*LT*V + (size_t)t*V + tid] = s;
  }
  __syncthreads();
  if (tid==0){
    float best = lg[0]; int bi=0;
    for(int v2=1;v2<V;v2++){ if(lg[v2]>best){best=lg[v2];bi=v2;} }
    vec_in[b]=bi;
  }
}

// ---------------- vn ----------------
__global__ __launch_bounds__(256) void vn_kernel(
    const float* __restrict__ v, float* __restrict__ vn){
  int row = blockIdx.x*4 + (threadIdx.x>>6);
  int lane = threadIdx.x & 63;
  const float* vr = v + (size_t)row*H;
  float s=0.f;
#pragma unroll
  for(int j=0;j<8;j++){ float xx = vr[lane + 64*j]; s += xx*xx; }
  s = wsum(s);
  if(lane==0) vn[row] = fmaxf(sqrtf(s), EPSF);
}

// ---------------- init decoder state ----------------
__global__ __launch_bounds__(256) void init_dec(
    const float* __restrict__ h0f, const float* __restrict__ hb0,
    ushort_t* __restrict__ H0h, ushort_t* __restrict__ H0l,
    ushort_t* __restrict__ QAh, ushort_t* __restrict__ QAl,
    int* __restrict__ vec_in){
  int i = blockIdx.x*256 + threadIdx.x;   // 65536
  int b = i>>9, u = i&511;
  float a = h0f[i];
  ushort_t hh = f2bu(a);
  size_t e0 = eidx(b,u,16);
  H0h[e0]=hh; H0l[e0]=f2bu(a - bu2f(hh));
  float c = hb0[i];
  ushort_t ch = f2bu(c);
  size_t e1 = eidx(b,u,32);
  QAh[e1]=ch; QAl[e1]=f2bu(c - bu2f(ch));
  if (i < B) vec_in[i] = 0;
}

// ---------------- h_final ----------------
__global__ __launch_bounds__(256) void copy_hfinal(
    const ushort_t* __restrict__ H0h, const ushort_t* __restrict__ H0l,
    const ushort_t* __restrict__ QAh, const ushort_t* __restrict__ QAl,
    float* __restrict__ out){
  int i = blockIdx.x*256 + threadIdx.x;  // 131072
  if (i < 65536){
    int b = i>>9, u = i&511;
    size_t e = eidx(b,u,16);
    out[i] = bu2f(H0h[e]) + bu2f(H0l[e]);
  } else {
    int k = i - 65536; int b = k>>9, u = k&511;
    size_t e = eidx(b,u,32);
    out[i] = bu2f(QAh[e]) + bu2f(QAl[e]);
  }
}

extern "C" void kernel_launch(void* const* d_in, const int* in_sizes, int n_in,
                              void* d_out, int out_size, void* d_ws, size_t ws_size,
                              hipStream_t stream) {
  (void)in_sizes; (void)n_in; (void)out_size;
  const float* x     = (const float*)d_in[0];
  const float* emb   = (const float*)d_in[2];
  const float* W_enc = (const float*)d_in[3];
  const float* b_enc = (const float*)d_in[4];
  const float* e0Wih = (const float*)d_in[5];
  const float* e0Whh = (const float*)d_in[6];
  const float* e0bih = (const float*)d_in[7];
  const float* e0bhh = (const float*)d_in[8];
  const float* e1Wih = (const float*)d_in[9];
  const float* e1Whh = (const float*)d_in[10];
  const float* e1bih = (const float*)d_in[11];
  const float* e1bhh = (const float*)d_in[12];
  const float* W_bi  = (const float*)d_in[13];
  const float* b_bi  = (const float*)d_in[14];
  const float* dWih  = (const float*)d_in[15];
  const float* dWhh  = (const float*)d_in[16];
  const float* dbih  = (const float*)d_in[17];
  const float* dbhh  = (const float*)d_in[18];
  const float* W_att = (const float*)d_in[19];
  const float* b_att = (const float*)d_in[20];
  const float* W_out = (const float*)d_in[21];
  const float* b_out = (const float*)d_in[22];

  char* wsb = (char*)d_ws;
  size_t o = 0;
  auto alloc = [&](size_t bytes)->char*{ char* r = wsb + o; o += (bytes + 255) & ~(size_t)255; return r; };

  ushort_t* y0h = (ushort_t*)alloc(67108864);
  ushort_t* y0l = (ushort_t*)alloc(67108864);
  float*    v   = (float*)   alloc(67108864);
  ushort_t* w0h = (ushort_t*)alloc(3145728);   // enc0 Whh pack
  ushort_t* w0l = (ushort_t*)alloc(3145728);
  ushort_t* w1xh= (ushort_t*)alloc(6291456);   // enc1 Wih
  ushort_t* w1xl= (ushort_t*)alloc(6291456);
  ushort_t* w1hh= (ushort_t*)alloc(3145728);   // enc1 Whh
  ushort_t* w1hl= (ushort_t*)alloc(3145728);
  ushort_t* wbih= (ushort_t*)alloc(1048576);   // W_bi halves
  ushort_t* wbil= (ushort_t*)alloc(1048576);
  ushort_t* dxh = (ushort_t*)alloc(3145728);   // dec Wih (both layers)
  ushort_t* dxl = (ushort_t*)alloc(3145728);
  ushort_t* dhh = (ushort_t*)alloc(3145728);   // dec Whh
  ushort_t* dhl = (ushort_t*)alloc(3145728);
  ushort_t* wah = (ushort_t*)alloc(1048576);   // W_att
  ushort_t* wal = (ushort_t*)alloc(1048576);
  ushort_t* eph = (ushort_t*)alloc(27648);     // emb pack
  ushort_t* epl = (ushort_t*)alloc(27648);
  float* F0  = (float*)alloc(12288);
  float* F1  = (float*)alloc(12288);
  float* bfE = (float*)alloc(12288);
  ushort_t* h1h = (ushort_t*)alloc(524288);    // enc1 state 2 slots
  ushort_t* h1l = (ushort_t*)alloc(524288);
  ushort_t* h0h = (ushort_t*)alloc(262144);    // dec l0 state 2 slots
  ushort_t* h0l = (ushort_t*)alloc(262144);
  ushort_t* qah = (ushort_t*)alloc(524288);    // q|a 2 slots
  ushort_t* qal = (ushort_t*)alloc(524288);
  float* hid = (float*)alloc(262144);
  float* vn  = (float*)alloc(131072);
  float* h0f = (float*)alloc(262144);
  float* hb0 = (float*)alloc(262144);
  int* vec_in = (int*)alloc(512);
  if (o > ws_size) return;

  const size_t H1S = 131072;  // elems per h1 slot-plane (128*1024)
  const size_t H0S = 65536;   // 128*512
  const size_t QAS = 131072;

  float* vec_out = (float*)d_out;
  float* h_final = vec_out + (size_t)B*LT*V;
  float* attn    = h_final + 2*B*H;

  // ---- prep: pack weights ----
  pack_w<<<(3072*512+255)/256, 256, 0, stream>>>(e0Whh, 512, 3072, 512, w0h, w0l);
  pack_w<<<(3072*1024+255)/256, 256, 0, stream>>>(e1Wih, 1024, 3072, 1024, w1xh, w1xl);
  pack_w<<<(3072*512+255)/256, 256, 0, stream>>>(e1Whh, 512, 3072, 512, w1hh, w1hl);
  pack_w<<<(512*512+255)/256, 256, 0, stream>>>(W_bi, 1024, 512, 512, wbih, wbil);
  pack_w<<<(512*512+255)/256, 256, 0, stream>>>(W_bi+512, 1024, 512, 512, wbih+262144, wbil+262144);
  pack_w<<<(3072*512+255)/256, 256, 0, stream>>>(dWih, 512, 3072, 512, dxh, dxl);
  pack_w<<<(3072*512+255)/256, 256, 0, stream>>>(dWhh, 512, 3072, 512, dhh, dhl);
  pack_w<<<(512*1024+255)/256, 256, 0, stream>>>(W_att, 1024, 512, 1024, wah, wal);
  pack_emb<<<(V*H+255)/256, 256, 0, stream>>>(emb, eph, epl);
  fuse_w0<<<768, 256, 0, stream>>>(e0Wih, W_enc, b_enc, e0bih, F0, F1, bfE);

  // ---- encoder layer 0 ----
  for (int t=0;t<LC;t++)
    enc0_step<<<256, 256, 0, stream>>>(t, x, F0, F1, bfE, w0h, w0l, e0bhh, y0h, y0l, h0f, hb0);

  // ---- encoder layer 1 + fused bi_fc (t=256 runs only v-blocks) ----
  for (int t=0;t<=LC;t++){
    int pin = (t&1)^1, pout = t&1;
    enc1_step<<<320, 256, 0, stream>>>(t, y0h, y0l,
        h1h + (size_t)pin*H1S, h1l + (size_t)pin*H1S,
        h1h + (size_t)pout*H1S, h1l + (size_t)pout*H1S,
        w1xh, w1xl, w1hh, w1hl, e1bih, e1bhh, wbih, wbil, b_bi, v);
  }

  vn_kernel<<<8192, 256, 0, stream>>>(v, vn);
  init_dec<<<256, 256, 0, stream>>>(h0f, hb0, h0h, h0l, qah, qal, vec_in);

  // ---- decoder ----
  for (int t=0;t<LT;t++){
    int pin = t&1, pout = pin^1;
    // layer 0: x = emb gather, h = h0p[pin] -> h0p[pout]
    dec_gru<<<128, 256, 0, stream>>>(vec_in, eph, epl,
        nullptr, nullptr, 16,
        h0h + (size_t)pin*H0S, h0l + (size_t)pin*H0S, 16,
        h0h + (size_t)pout*H0S, h0l + (size_t)pout*H0S, 16,
        dxh, dxl, dhh, dhl, dbih, dbhh);
    // layer 1: x = h0p[pout], h = qa[pin].q -> qa[pout].q
    dec_gru<<<128, 256, 0, stream>>>(nullptr, nullptr, nullptr,
        h0h + (size_t)pout*H0S, h0l + (size_t)pout*H0S, 16,
        qah + (size_t)pin*QAS, qal + (size_t)pin*QAS, 32,
        qah + (size_t)pout*QAS, qal + (size_t)pout*QAS, 32,
        dxh + 786432, dxl + 786432, dhh + 786432, dhl + 786432,
        dbih + H3, dbhh + H3);
    attn_step<<<B, 256, 0, stream>>>(
        qah + (size_t)pout*QAS, qal + (size_t)pout*QAS,
        qah + (size_t)pout*QAS, qal + (size_t)pout*QAS,
        v, vn, attn, t);
    att_fc<<<32, 256, 0, stream>>>(
        qah + (size_t)pout*QAS, qal + (size_t)pout*QAS,
        wah, wal, b_att, hid);
    logits_step<<<B, 256, 0, stream>>>(hid, W_out, b_out, vec_out, vec_in, t);
  }
  // final states: after t=63 (odd), pout=0 -> slot 0
  copy_hfinal<<<512, 256, 0, stream>>>(h0h, h0l, qah, qal, h_final);
}